// Round 16
// baseline (42.429 us; speedup 1.0000x reference)
//
#include <hip/hip_runtime.h>
#include <utility>

#define DEV __device__ __forceinline__

constexpr int NV = 16;
constexpr float STEP = 0.1f;
constexpr int LDA = 20;  // padded LDS row stride: 80 B -> 2-way bank alias (free)

// Schedule (R12/R14, proven 0.0156 -- the frontier; R13/R15 mapped the cliff):
// iters 1-4 exact; {build,apply}x6 (applies span-1); build 17; applies
// 18,19,20 (spans 1,2,3). 11 builds / 9 applies.
constexpr int N_EXACT = 4;
constexpr int N_PAIR = 6;

// ---- compile-time for loop (DPP ctrl / register indices must be ICEs) ----
template <class F, int... Is>
DEV void sf_impl(F&& f, std::integer_sequence<int, Is...>) {
  (f(std::integral_constant<int, Is>{}), ...);
}
template <int N, class F>
DEV void static_for(F&& f) {
  sf_impl(f, std::make_integer_sequence<int, N>{});
}

// ---- broadcast lane Q within each quad (single v_mov_b32_dpp; intrinsic so
// the compiler's hazard recognizer inserts DPP wait states) ----
template <int Q>
DEV float qbcast(float v) {
#if __has_builtin(__builtin_amdgcn_mov_dpp)
  int r = __builtin_amdgcn_mov_dpp(__float_as_int(v), Q * 0x55, 0xF, 0xF, true);
#else
  int iv = __float_as_int(v);
  int r = __builtin_amdgcn_update_dpp(iv, iv, Q * 0x55, 0xF, 0xF, true);
#endif
  return __int_as_float(r);
}

DEV float rcp_fast(float x) { return __builtin_amdgcn_rcpf(x); }

// One full Newton iteration: fresh M = A + diag(3y^2/cos), residual, and
// Gauss-Jordan solve. If STORE, the per-step elimination factors f[] and the
// pivot inverses survive (nfS/dginv) for the frozen-apply iterations.
template <bool STORE>
DEV void newton_full_iter(float (&y)[4], const float (&x)[4],
                          const float* __restrict__ Arow0,
                          const float (&eqf)[4], const float (&neqf)[4],
                          int l, float (&nfS)[16][4], float (&dginv)[4]) {
  // 1) M <- A (LDS reads issue first; waitcnt lands before first use)
  float M[4][16];
  static_for<4>([&](auto MM) {
    constexpr int m = MM.value;
    static_for<4>([&](auto TT) {
      constexpr int t = TT.value;
      float4 a4 = *reinterpret_cast<const float4*>(Arow0 + m * LDA + 4 * t);
      M[m][4 * t + 0] = a4.x; M[m][4 * t + 1] = a4.y;
      M[m][4 * t + 2] = a4.z; M[m][4 * t + 3] = a4.w;
    });
  });

  // 2) trig + diag term + b init (hw v_sin/v_cos fine at O(1) rad)
  float s4[4], rc[4], tdiag[4], b[4];
#pragma unroll
  for (int m = 0; m < 4; ++m) {
    float yy = y[m];
    float y2 = yy * yy;
    s4[m] = __sinf(yy);
    float c = __cosf(yy);
    rc[m] = rcp_fast(c);
    tdiag[m] = 3.0f * y2 * rc[m];
    b[m] = x[m] - y2 * yy;
  }
  float sf[16];
  static_for<16>([&](auto JJ) {
    constexpr int j = JJ.value;
    sf[j] = qbcast<(j >> 2)>(s4[j & 3]);
  });

  // 3) residual b -= A*sin(y)  (uses M == A, before diag add)
  static_for<4>([&](auto MM) {
    constexpr int m = MM.value;
    static_for<16>([&](auto JJ) {
      constexpr int j = JJ.value;
      b[m] = __builtin_fmaf(-M[m][j], sf[j], b[m]);
    });
  });
  // diag add: row 4l+m's diagonal is col block t==l, slot m
  static_for<4>([&](auto MM) {
    constexpr int m = MM.value;
    static_for<4>([&](auto TT) {
      constexpr int t = TT.value;
      M[m][4 * t + m] = __builtin_fmaf(eqf[t], tdiag[m], M[m][4 * t + m]);
    });
  });

  // 4) unpivoted Gauss-Jordan (M diag-dominant by construction)
  static_for<16>([&](auto KK) {
    constexpr int k = KK.value;
    constexpr int q = k >> 2, mk = k & 3;
    float invl = rcp_fast(M[mk][k]);  // local rcp before bcast
    float inv = qbcast<q>(invl);
    float bk = qbcast<q>(b[mk]);
    float f[4];
#pragma unroll
    for (int m = 0; m < 4; ++m) f[m] = M[m][k] * inv;
    f[mk] *= neqf[q];                      // owner lane keeps its pivot row
    dginv[mk] = (l == q) ? inv : dginv[mk];  // capture own pivot inverse
    static_for<16 - k - 1>([&](auto JJ) {
      constexpr int j = k + 1 + JJ.value;
      float rkj = qbcast<q>(M[mk][j]);
#pragma unroll
      for (int m = 0; m < 4; ++m) M[m][j] = __builtin_fmaf(-f[m], rkj, M[m][j]);
    });
#pragma unroll
    for (int m = 0; m < 4; ++m) b[m] = __builtin_fmaf(-f[m], bk, b[m]);
    if constexpr (STORE) {
#pragma unroll
      for (int m = 0; m < 4; ++m) nfS[k][m] = f[m];
    }
  });

  // 5) u = b*dginv ; delta = u/cos ; y += STEP*delta
#pragma unroll
  for (int m = 0; m < 4; ++m) {
    float u = b[m] * dginv[m];
    y[m] = __builtin_fmaf(STEP, u * rc[m], y[m]);
  }
}

// Frozen-factorization iteration: fresh (exact) residual, replay stored
// elimination. ~215 VALU slots vs ~960 for a full iteration.
DEV void newton_apply_iter(float (&y)[4], const float (&x)[4],
                           const float* __restrict__ Arow0,
                           const float (&nfS)[16][4], const float (&dginv)[4]) {
  float s4[4], rc[4], b[4];
#pragma unroll
  for (int m = 0; m < 4; ++m) {
    float yy = y[m];
    float y2 = yy * yy;
    s4[m] = __sinf(yy);
    rc[m] = rcp_fast(__cosf(yy));
    b[m] = x[m] - y2 * yy;
  }
  float sf[16];
  static_for<16>([&](auto JJ) {
    constexpr int j = JJ.value;
    sf[j] = qbcast<(j >> 2)>(s4[j & 3]);
  });
  // residual from A (LDS re-read; LDS pipe is idle anyway)
  static_for<4>([&](auto MM) {
    constexpr int m = MM.value;
    static_for<4>([&](auto TT) {
      constexpr int t = TT.value;
      float4 a4 = *reinterpret_cast<const float4*>(Arow0 + m * LDA + 4 * t);
      b[m] = __builtin_fmaf(-a4.x, sf[4 * t + 0], b[m]);
      b[m] = __builtin_fmaf(-a4.y, sf[4 * t + 1], b[m]);
      b[m] = __builtin_fmaf(-a4.z, sf[4 * t + 2], b[m]);
      b[m] = __builtin_fmaf(-a4.w, sf[4 * t + 3], b[m]);
    });
  });
  // replay stored elimination on b
  static_for<16>([&](auto KK) {
    constexpr int k = KK.value;
    constexpr int q = k >> 2, mk = k & 3;
    float bk = qbcast<q>(b[mk]);
#pragma unroll
    for (int m = 0; m < 4; ++m) b[m] = __builtin_fmaf(-nfS[k][m], bk, b[m]);
  });
#pragma unroll
  for (int m = 0; m < 4; ++m) {
    float u = b[m] * dginv[m];
    y[m] = __builtin_fmaf(STEP, u * rc[m], y[m]);
  }
}

// One quad per system; lane l owns rows {4l..4l+3}. u-substitution:
// solve (A + diag(3y^2/cos)) u = b, delta = u/cos. A staged in LDS.
// R16 change: odd blocks stagger ~2.2k cycles at start. Co-resident waves
// (2/SIMD, identical code, simultaneous start) stall IN PHASE on the GJ
// spine; a half-build phase offset lets one wave's fma bursts cover the
// other's serial links. Timing-only: output bit-identical to R14.
__global__ __attribute__((amdgpu_flat_work_group_size(64, 64),
                          amdgpu_waves_per_eu(2, 2)))
void newton16(const float* __restrict__ y0, const float* __restrict__ xin,
              const float* __restrict__ Ain, float* __restrict__ out, int B) {
  __shared__ float Alds[NV * LDA];
  {  // 64 threads stage exactly 16 rows x 4 float4 segments
    const int t = threadIdx.x;
    const int row = t >> 2, seg = t & 3;
    float4 a = *reinterpret_cast<const float4*>(Ain + row * NV + seg * 4);
    *reinterpret_cast<float4*>(&Alds[row * LDA + seg * 4]) = a;
  }
  __syncthreads();  // 1-wave block: effectively free

  // Desynchronize: odd blocks sleep ~2240 cy (5 x s_sleep(7) ~ 5x448 cy).
  // s_sleep has no architectural side effects -> results unchanged.
  if (blockIdx.x & 1) {
    __builtin_amdgcn_s_sleep(7);
    __builtin_amdgcn_s_sleep(7);
    __builtin_amdgcn_s_sleep(7);
    __builtin_amdgcn_s_sleep(7);
    __builtin_amdgcn_s_sleep(7);
  }

  const int tid = blockIdx.x * blockDim.x + threadIdx.x;
  const int g = tid >> 2, l = tid & 3;
  if (g >= B) return;

  float y[4], x[4];
  {
    float4 t = *reinterpret_cast<const float4*>(y0 + g * NV + 4 * l);
    y[0] = t.x; y[1] = t.y; y[2] = t.z; y[3] = t.w;
    float4 u = *reinterpret_cast<const float4*>(xin + g * NV + 4 * l);
    x[0] = u.x; x[1] = u.y; x[2] = u.z; x[3] = u.w;
  }

  float eqf[4], neqf[4];
#pragma unroll
  for (int q = 0; q < 4; ++q) {
    eqf[q] = (l == q) ? 1.0f : 0.0f;
    neqf[q] = 1.0f - eqf[q];
  }

  const float* __restrict__ Arow0 = &Alds[(4 * l) * LDA];

  float nfS[16][4];  // frozen elimination factors (refreshed at each store-build)
  float dginv[4] = {1.0f, 1.0f, 1.0f, 1.0f};

#pragma unroll 1  // iters 1-4: exact
  for (int it = 0; it < N_EXACT; ++it)
    newton_full_iter<false>(y, x, Arow0, eqf, neqf, l, nfS, dginv);

#pragma unroll 1  // iters 5-16: {store-build, span-1 apply} x6
  for (int p = 0; p < N_PAIR; ++p) {
    newton_full_iter<true>(y, x, Arow0, eqf, neqf, l, nfS, dginv);
    newton_apply_iter(y, x, Arow0, nfS, dginv);
  }

  // iters 17-20: store-build + applies (spans 1,2,3)
  newton_full_iter<true>(y, x, Arow0, eqf, neqf, l, nfS, dginv);
  newton_apply_iter(y, x, Arow0, nfS, dginv);
  newton_apply_iter(y, x, Arow0, nfS, dginv);
  newton_apply_iter(y, x, Arow0, nfS, dginv);

  float4 o;
  o.x = y[0]; o.y = y[1]; o.z = y[2]; o.w = y[3];
  *reinterpret_cast<float4*>(out + g * NV + 4 * l) = o;
}

extern "C" void kernel_launch(void* const* d_in, const int* in_sizes, int n_in,
                              void* d_out, int out_size, void* d_ws, size_t ws_size,
                              hipStream_t stream) {
  const float* y = (const float*)d_in[0];
  const float* x = (const float*)d_in[1];
  const float* A = (const float*)d_in[2];
  float* out = (float*)d_out;
  const int B = in_sizes[0] / NV;  // 32768
  const int threads = B * 4;       // one quad per system
  dim3 block(64);                  // 1 wave/block
  dim3 grid((threads + block.x - 1) / block.x);
  hipLaunchKernelGGL(newton16, grid, block, 0, stream, y, x, A, out, B);
}

// Round 17
// 41.475 us; speedup vs baseline: 1.0230x; 1.0230x over previous
//
#include <hip/hip_runtime.h>
#include <utility>

#define DEV __device__ __forceinline__

constexpr int NV = 16;
constexpr float STEP = 0.1f;
constexpr int LDA = 20;  // padded LDS row stride: 80 B -> 2-way bank alias (free)

// Schedule (R12/R14 frontier, proven 0.0156): iters 1-4 exact; {build,apply}x6
// (applies span-1); build 17; applies 18,19,20 (spans 1,2,3).
constexpr int N_EXACT = 4;
constexpr int N_PAIR = 6;

// ---- compile-time for loop (DPP ctrl / register indices must be ICEs) ----
template <class F, int... Is>
DEV void sf_impl(F&& f, std::integer_sequence<int, Is...>) {
  (f(std::integral_constant<int, Is>{}), ...);
}
template <int N, class F>
DEV void static_for(F&& f) {
  sf_impl(f, std::make_integer_sequence<int, N>{});
}

// ---- broadcast lane Q within each quad (single v_mov_b32_dpp; intrinsic so
// the compiler's hazard recognizer inserts DPP wait states) ----
template <int Q>
DEV float qbcast(float v) {
#if __has_builtin(__builtin_amdgcn_mov_dpp)
  int r = __builtin_amdgcn_mov_dpp(__float_as_int(v), Q * 0x55, 0xF, 0xF, true);
#else
  int iv = __float_as_int(v);
  int r = __builtin_amdgcn_update_dpp(iv, iv, Q * 0x55, 0xF, 0xF, true);
#endif
  return __int_as_float(r);
}

DEV float rcp_fast(float x) { return __builtin_amdgcn_rcpf(x); }

// One full Newton iteration. If NRINV: pivot inverses come from a 2-VALU-op
// Newton refinement of the PREVIOUS build's stored inverses (invS) instead of
// the quarter-rate v_rcp on the 16x-repeated serial spine. Error: (pivot
// drift)^2 <= ~1e-4..1e-2 rel, self-correcting across builds. Exact builds
// (NRINV=false) seed invS with real v_rcp.
template <bool STORE, bool NRINV>
DEV void newton_full_iter(float (&y)[4], const float (&x)[4],
                          const float* __restrict__ Arow0,
                          const float (&eqf)[4], const float (&neqf)[4],
                          int l, float (&nfS)[16][4], float (&dginv)[4],
                          float (&invS)[16]) {
  // 1) M <- A (LDS reads issue first; latency hides under trig below)
  float M[4][16];
  static_for<4>([&](auto MM) {
    constexpr int m = MM.value;
    static_for<4>([&](auto TT) {
      constexpr int t = TT.value;
      float4 a4 = *reinterpret_cast<const float4*>(Arow0 + m * LDA + 4 * t);
      M[m][4 * t + 0] = a4.x; M[m][4 * t + 1] = a4.y;
      M[m][4 * t + 2] = a4.z; M[m][4 * t + 3] = a4.w;
    });
  });

  // 2) trig + diag term + b init (hw v_sin/v_cos fine at O(1) rad)
  float s4[4], rc[4], tdiag[4], b[4];
#pragma unroll
  for (int m = 0; m < 4; ++m) {
    float yy = y[m];
    float y2 = yy * yy;
    s4[m] = __sinf(yy);
    float c = __cosf(yy);
    rc[m] = rcp_fast(c);
    tdiag[m] = 3.0f * y2 * rc[m];
    b[m] = x[m] - y2 * yy;
  }
  float sf[16];
  static_for<16>([&](auto JJ) {
    constexpr int j = JJ.value;
    sf[j] = qbcast<(j >> 2)>(s4[j & 3]);
  });

  // 3) residual b -= A*sin(y)  (uses M == A, before diag add)
  static_for<4>([&](auto MM) {
    constexpr int m = MM.value;
    static_for<16>([&](auto JJ) {
      constexpr int j = JJ.value;
      b[m] = __builtin_fmaf(-M[m][j], sf[j], b[m]);
    });
  });
  // diag add: row 4l+m's diagonal is col block t==l, slot m
  static_for<4>([&](auto MM) {
    constexpr int m = MM.value;
    static_for<4>([&](auto TT) {
      constexpr int t = TT.value;
      M[m][4 * t + m] = __builtin_fmaf(eqf[t], tdiag[m], M[m][4 * t + m]);
    });
  });

  // 4) unpivoted Gauss-Jordan (M diag-dominant by construction)
  static_for<16>([&](auto KK) {
    constexpr int k = KK.value;
    constexpr int q = k >> 2, mk = k & 3;
    float invl;
    if constexpr (NRINV) {
      // NR from previous build's inverse: 2 full-rate ops, no trans on spine
      float p = M[mk][k];
      float t = __builtin_fmaf(-p, invS[k], 2.0f);
      invl = invS[k] * t;
    } else {
      invl = rcp_fast(M[mk][k]);  // local rcp before bcast
    }
    float inv = qbcast<q>(invl);
    invS[k] = inv;  // persist (all lanes) for the next NRINV build
    float bk = qbcast<q>(b[mk]);
    float f[4];
#pragma unroll
    for (int m = 0; m < 4; ++m) f[m] = M[m][k] * inv;
    f[mk] *= neqf[q];                      // owner lane keeps its pivot row
    dginv[mk] = (l == q) ? inv : dginv[mk];  // capture own pivot inverse
    static_for<16 - k - 1>([&](auto JJ) {
      constexpr int j = k + 1 + JJ.value;
      float rkj = qbcast<q>(M[mk][j]);
#pragma unroll
      for (int m = 0; m < 4; ++m) M[m][j] = __builtin_fmaf(-f[m], rkj, M[m][j]);
    });
#pragma unroll
    for (int m = 0; m < 4; ++m) b[m] = __builtin_fmaf(-f[m], bk, b[m]);
    if constexpr (STORE) {
#pragma unroll
      for (int m = 0; m < 4; ++m) nfS[k][m] = f[m];
    }
  });

  // 5) u = b*dginv ; delta = u/cos ; y += STEP*delta
#pragma unroll
  for (int m = 0; m < 4; ++m) {
    float u = b[m] * dginv[m];
    y[m] = __builtin_fmaf(STEP, u * rc[m], y[m]);
  }
}

// Frozen-factorization iteration. R17 change: ALL 16 A-loads hoisted to the
// top (statically-indexed regs) so LDS first-use latency hides under the trig
// + sin-broadcast head -- the apply was LDS-latency exposed (R12 vs R14:
// marginal apply cost ~= marginal build cost despite 4.4x fewer VALU slots).
DEV void newton_apply_iter(float (&y)[4], const float (&x)[4],
                           const float* __restrict__ Arow0,
                           const float (&nfS)[16][4], const float (&dginv)[4]) {
  // issue all A reads first
  float4 a4s[16];
  static_for<4>([&](auto MM) {
    constexpr int m = MM.value;
    static_for<4>([&](auto TT) {
      constexpr int t = TT.value;
      a4s[m * 4 + t] = *reinterpret_cast<const float4*>(Arow0 + m * LDA + 4 * t);
    });
  });

  float s4[4], rc[4], b[4];
#pragma unroll
  for (int m = 0; m < 4; ++m) {
    float yy = y[m];
    float y2 = yy * yy;
    s4[m] = __sinf(yy);
    rc[m] = rcp_fast(__cosf(yy));
    b[m] = x[m] - y2 * yy;
  }
  float sf[16];
  static_for<16>([&](auto JJ) {
    constexpr int j = JJ.value;
    sf[j] = qbcast<(j >> 2)>(s4[j & 3]);
  });
  // residual from the pre-loaded A regs
  static_for<4>([&](auto MM) {
    constexpr int m = MM.value;
    static_for<4>([&](auto TT) {
      constexpr int t = TT.value;
      float4 a4 = a4s[m * 4 + t];
      b[m] = __builtin_fmaf(-a4.x, sf[4 * t + 0], b[m]);
      b[m] = __builtin_fmaf(-a4.y, sf[4 * t + 1], b[m]);
      b[m] = __builtin_fmaf(-a4.z, sf[4 * t + 2], b[m]);
      b[m] = __builtin_fmaf(-a4.w, sf[4 * t + 3], b[m]);
    });
  });
  // replay stored elimination on b
  static_for<16>([&](auto KK) {
    constexpr int k = KK.value;
    constexpr int q = k >> 2, mk = k & 3;
    float bk = qbcast<q>(b[mk]);
#pragma unroll
    for (int m = 0; m < 4; ++m) b[m] = __builtin_fmaf(-nfS[k][m], bk, b[m]);
  });
#pragma unroll
  for (int m = 0; m < 4; ++m) {
    float u = b[m] * dginv[m];
    y[m] = __builtin_fmaf(STEP, u * rc[m], y[m]);
  }
}

// One quad per system; lane l owns rows {4l..4l+3}. u-substitution:
// solve (A + diag(3y^2/cos)) u = b, delta = u/cos. A staged in LDS.
__global__ __attribute__((amdgpu_flat_work_group_size(64, 64),
                          amdgpu_waves_per_eu(2, 2)))
void newton16(const float* __restrict__ y0, const float* __restrict__ xin,
              const float* __restrict__ Ain, float* __restrict__ out, int B) {
  __shared__ float Alds[NV * LDA];
  {  // 64 threads stage exactly 16 rows x 4 float4 segments
    const int t = threadIdx.x;
    const int row = t >> 2, seg = t & 3;
    float4 a = *reinterpret_cast<const float4*>(Ain + row * NV + seg * 4);
    *reinterpret_cast<float4*>(&Alds[row * LDA + seg * 4]) = a;
  }
  __syncthreads();  // 1-wave block: effectively free

  const int tid = blockIdx.x * blockDim.x + threadIdx.x;
  const int g = tid >> 2, l = tid & 3;
  if (g >= B) return;

  float y[4], x[4];
  {
    float4 t = *reinterpret_cast<const float4*>(y0 + g * NV + 4 * l);
    y[0] = t.x; y[1] = t.y; y[2] = t.z; y[3] = t.w;
    float4 u = *reinterpret_cast<const float4*>(xin + g * NV + 4 * l);
    x[0] = u.x; x[1] = u.y; x[2] = u.z; x[3] = u.w;
  }

  float eqf[4], neqf[4];
#pragma unroll
  for (int q = 0; q < 4; ++q) {
    eqf[q] = (l == q) ? 1.0f : 0.0f;
    neqf[q] = 1.0f - eqf[q];
  }

  const float* __restrict__ Arow0 = &Alds[(4 * l) * LDA];

  float nfS[16][4];  // frozen elimination factors (refreshed at store-builds)
  float dginv[4] = {1.0f, 1.0f, 1.0f, 1.0f};
  float invS[16];    // pivot inverses persisted across builds (NR seed)

#pragma unroll 1  // iters 1-4: exact, real v_rcp (seeds invS)
  for (int it = 0; it < N_EXACT; ++it)
    newton_full_iter<false, false>(y, x, Arow0, eqf, neqf, l, nfS, dginv, invS);

#pragma unroll 1  // iters 5-16: {store-build (NR pivots), span-1 apply} x6
  for (int p = 0; p < N_PAIR; ++p) {
    newton_full_iter<true, true>(y, x, Arow0, eqf, neqf, l, nfS, dginv, invS);
    newton_apply_iter(y, x, Arow0, nfS, dginv);
  }

  // iters 17-20: store-build (NR) + applies (spans 1,2,3)
  newton_full_iter<true, true>(y, x, Arow0, eqf, neqf, l, nfS, dginv, invS);
  newton_apply_iter(y, x, Arow0, nfS, dginv);
  newton_apply_iter(y, x, Arow0, nfS, dginv);
  newton_apply_iter(y, x, Arow0, nfS, dginv);

  float4 o;
  o.x = y[0]; o.y = y[1]; o.z = y[2]; o.w = y[3];
  *reinterpret_cast<float4*>(out + g * NV + 4 * l) = o;
}

extern "C" void kernel_launch(void* const* d_in, const int* in_sizes, int n_in,
                              void* d_out, int out_size, void* d_ws, size_t ws_size,
                              hipStream_t stream) {
  const float* y = (const float*)d_in[0];
  const float* x = (const float*)d_in[1];
  const float* A = (const float*)d_in[2];
  float* out = (float*)d_out;
  const int B = in_sizes[0] / NV;  // 32768
  const int threads = B * 4;       // one quad per system
  dim3 block(64);                  // 1 wave/block
  dim3 grid((threads + block.x - 1) / block.x);
  hipLaunchKernelGGL(newton16, grid, block, 0, stream, y, x, A, out, B);
}

// Round 18
// 39.724 us; speedup vs baseline: 1.0681x; 1.0441x over previous
//
#include <hip/hip_runtime.h>
#include <utility>

#define DEV __device__ __forceinline__

constexpr int NV = 16;
constexpr float STEP = 0.1f;
constexpr int LDA = 20;  // padded LDS row stride: 80 B -> 2-way bank alias (free)

// Schedule (20 iters, 10 builds / 10 applies):
//   1-4 exact; {b,a}x2 (5-8); {b,a,a}x2 (9-14); b15,a16; b17,a18,a19,a20.
// Error model (pass: R14=8.09u/0.0078-0.0156, R12, R8; fail: R13 early
// applies, R15 mid span-3): this = 9.44u, no applies <6, max mid span 2,
// tail identical to R14's proven {s1,s2,s3}.

// ---- compile-time for loop (DPP ctrl / register indices must be ICEs) ----
template <class F, int... Is>
DEV void sf_impl(F&& f, std::integer_sequence<int, Is...>) {
  (f(std::integral_constant<int, Is>{}), ...);
}
template <int N, class F>
DEV void static_for(F&& f) {
  sf_impl(f, std::make_integer_sequence<int, N>{});
}

// ---- broadcast lane Q within each quad (single v_mov_b32_dpp; intrinsic so
// the compiler's hazard recognizer inserts DPP wait states) ----
template <int Q>
DEV float qbcast(float v) {
#if __has_builtin(__builtin_amdgcn_mov_dpp)
  int r = __builtin_amdgcn_mov_dpp(__float_as_int(v), Q * 0x55, 0xF, 0xF, true);
#else
  int iv = __float_as_int(v);
  int r = __builtin_amdgcn_update_dpp(iv, iv, Q * 0x55, 0xF, 0xF, true);
#endif
  return __int_as_float(r);
}

DEV float rcp_fast(float x) { return __builtin_amdgcn_rcpf(x); }

// One full Newton iteration. NRINV: pivot inverses via 2-op Newton refinement
// of the previous build's stored inverses (no trans op on the 16x serial
// spine); exact builds seed invS with real v_rcp. R17 measured this
// accuracy-NEUTRAL-or-better (0.0156 -> 0.0078) and time-neutral.
template <bool STORE, bool NRINV>
DEV void newton_full_iter(float (&y)[4], const float (&x)[4],
                          const float* __restrict__ Arow0,
                          const float (&eqf)[4], const float (&neqf)[4],
                          int l, float (&nfS)[16][4], float (&dginv)[4],
                          float (&invS)[16]) {
  // 1) M <- A (LDS reads issue first; latency hides under trig below)
  float M[4][16];
  static_for<4>([&](auto MM) {
    constexpr int m = MM.value;
    static_for<4>([&](auto TT) {
      constexpr int t = TT.value;
      float4 a4 = *reinterpret_cast<const float4*>(Arow0 + m * LDA + 4 * t);
      M[m][4 * t + 0] = a4.x; M[m][4 * t + 1] = a4.y;
      M[m][4 * t + 2] = a4.z; M[m][4 * t + 3] = a4.w;
    });
  });

  // 2) trig + diag term + b init (hw v_sin/v_cos fine at O(1) rad)
  float s4[4], rc[4], tdiag[4], b[4];
#pragma unroll
  for (int m = 0; m < 4; ++m) {
    float yy = y[m];
    float y2 = yy * yy;
    s4[m] = __sinf(yy);
    float c = __cosf(yy);
    rc[m] = rcp_fast(c);
    tdiag[m] = 3.0f * y2 * rc[m];
    b[m] = x[m] - y2 * yy;
  }
  float sf[16];
  static_for<16>([&](auto JJ) {
    constexpr int j = JJ.value;
    sf[j] = qbcast<(j >> 2)>(s4[j & 3]);
  });

  // 3) residual b -= A*sin(y)  (uses M == A, before diag add)
  static_for<4>([&](auto MM) {
    constexpr int m = MM.value;
    static_for<16>([&](auto JJ) {
      constexpr int j = JJ.value;
      b[m] = __builtin_fmaf(-M[m][j], sf[j], b[m]);
    });
  });
  // diag add: row 4l+m's diagonal is col block t==l, slot m
  static_for<4>([&](auto MM) {
    constexpr int m = MM.value;
    static_for<4>([&](auto TT) {
      constexpr int t = TT.value;
      M[m][4 * t + m] = __builtin_fmaf(eqf[t], tdiag[m], M[m][4 * t + m]);
    });
  });

  // 4) unpivoted Gauss-Jordan (M diag-dominant by construction)
  static_for<16>([&](auto KK) {
    constexpr int k = KK.value;
    constexpr int q = k >> 2, mk = k & 3;
    float invl;
    if constexpr (NRINV) {
      float p = M[mk][k];
      float t = __builtin_fmaf(-p, invS[k], 2.0f);
      invl = invS[k] * t;  // 2 full-rate ops replace quarter-rate v_rcp
    } else {
      invl = rcp_fast(M[mk][k]);
    }
    float inv = qbcast<q>(invl);
    invS[k] = inv;  // persist (all lanes) for the next NRINV build
    float bk = qbcast<q>(b[mk]);
    float f[4];
#pragma unroll
    for (int m = 0; m < 4; ++m) f[m] = M[m][k] * inv;
    f[mk] *= neqf[q];                      // owner lane keeps its pivot row
    dginv[mk] = (l == q) ? inv : dginv[mk];  // capture own pivot inverse
    static_for<16 - k - 1>([&](auto JJ) {
      constexpr int j = k + 1 + JJ.value;
      float rkj = qbcast<q>(M[mk][j]);
#pragma unroll
      for (int m = 0; m < 4; ++m) M[m][j] = __builtin_fmaf(-f[m], rkj, M[m][j]);
    });
#pragma unroll
    for (int m = 0; m < 4; ++m) b[m] = __builtin_fmaf(-f[m], bk, b[m]);
    if constexpr (STORE) {
#pragma unroll
      for (int m = 0; m < 4; ++m) nfS[k][m] = f[m];
    }
  });

  // 5) u = b*dginv ; delta = u/cos ; y += STEP*delta
#pragma unroll
  for (int m = 0; m < 4; ++m) {
    float u = b[m] * dginv[m];
    y[m] = __builtin_fmaf(STEP, u * rc[m], y[m]);
  }
}

// Frozen-factorization iteration (fresh exact residual, replay stored
// elimination): ~215 VALU slots vs ~960. A-loads hoisted to the top (R17).
DEV void newton_apply_iter(float (&y)[4], const float (&x)[4],
                           const float* __restrict__ Arow0,
                           const float (&nfS)[16][4], const float (&dginv)[4]) {
  float4 a4s[16];
  static_for<4>([&](auto MM) {
    constexpr int m = MM.value;
    static_for<4>([&](auto TT) {
      constexpr int t = TT.value;
      a4s[m * 4 + t] = *reinterpret_cast<const float4*>(Arow0 + m * LDA + 4 * t);
    });
  });

  float s4[4], rc[4], b[4];
#pragma unroll
  for (int m = 0; m < 4; ++m) {
    float yy = y[m];
    float y2 = yy * yy;
    s4[m] = __sinf(yy);
    rc[m] = rcp_fast(__cosf(yy));
    b[m] = x[m] - y2 * yy;
  }
  float sf[16];
  static_for<16>([&](auto JJ) {
    constexpr int j = JJ.value;
    sf[j] = qbcast<(j >> 2)>(s4[j & 3]);
  });
  static_for<4>([&](auto MM) {
    constexpr int m = MM.value;
    static_for<4>([&](auto TT) {
      constexpr int t = TT.value;
      float4 a4 = a4s[m * 4 + t];
      b[m] = __builtin_fmaf(-a4.x, sf[4 * t + 0], b[m]);
      b[m] = __builtin_fmaf(-a4.y, sf[4 * t + 1], b[m]);
      b[m] = __builtin_fmaf(-a4.z, sf[4 * t + 2], b[m]);
      b[m] = __builtin_fmaf(-a4.w, sf[4 * t + 3], b[m]);
    });
  });
  static_for<16>([&](auto KK) {
    constexpr int k = KK.value;
    constexpr int q = k >> 2, mk = k & 3;
    float bk = qbcast<q>(b[mk]);
#pragma unroll
    for (int m = 0; m < 4; ++m) b[m] = __builtin_fmaf(-nfS[k][m], bk, b[m]);
  });
#pragma unroll
  for (int m = 0; m < 4; ++m) {
    float u = b[m] * dginv[m];
    y[m] = __builtin_fmaf(STEP, u * rc[m], y[m]);
  }
}

// One quad per system; lane l owns rows {4l..4l+3}. u-substitution:
// solve (A + diag(3y^2/cos)) u = b, delta = u/cos. A staged in LDS.
__global__ __attribute__((amdgpu_flat_work_group_size(64, 64),
                          amdgpu_waves_per_eu(2, 2)))
void newton16(const float* __restrict__ y0, const float* __restrict__ xin,
              const float* __restrict__ Ain, float* __restrict__ out, int B) {
  __shared__ float Alds[NV * LDA];
  {  // 64 threads stage exactly 16 rows x 4 float4 segments
    const int t = threadIdx.x;
    const int row = t >> 2, seg = t & 3;
    float4 a = *reinterpret_cast<const float4*>(Ain + row * NV + seg * 4);
    *reinterpret_cast<float4*>(&Alds[row * LDA + seg * 4]) = a;
  }
  __syncthreads();  // 1-wave block: effectively free

  const int tid = blockIdx.x * blockDim.x + threadIdx.x;
  const int g = tid >> 2, l = tid & 3;
  if (g >= B) return;

  float y[4], x[4];
  {
    float4 t = *reinterpret_cast<const float4*>(y0 + g * NV + 4 * l);
    y[0] = t.x; y[1] = t.y; y[2] = t.z; y[3] = t.w;
    float4 u = *reinterpret_cast<const float4*>(xin + g * NV + 4 * l);
    x[0] = u.x; x[1] = u.y; x[2] = u.z; x[3] = u.w;
  }

  float eqf[4], neqf[4];
#pragma unroll
  for (int q = 0; q < 4; ++q) {
    eqf[q] = (l == q) ? 1.0f : 0.0f;
    neqf[q] = 1.0f - eqf[q];
  }

  const float* __restrict__ Arow0 = &Alds[(4 * l) * LDA];

  float nfS[16][4];  // frozen elimination factors (refreshed at store-builds)
  float dginv[4] = {1.0f, 1.0f, 1.0f, 1.0f};
  float invS[16];    // pivot inverses persisted across builds (NR seed)

#pragma unroll 1  // iters 1-4: exact, real v_rcp (seeds invS)
  for (int it = 0; it < 4; ++it)
    newton_full_iter<false, false>(y, x, Arow0, eqf, neqf, l, nfS, dginv, invS);

#pragma unroll 1  // iters 5-8: {store-build, apply} x2 (span 1)
  for (int p = 0; p < 2; ++p) {
    newton_full_iter<true, true>(y, x, Arow0, eqf, neqf, l, nfS, dginv, invS);
    newton_apply_iter(y, x, Arow0, nfS, dginv);
  }

#pragma unroll 1  // iters 9-14: {store-build, apply, apply} x2 (spans 1,2)
  for (int p = 0; p < 2; ++p) {
    newton_full_iter<true, true>(y, x, Arow0, eqf, neqf, l, nfS, dginv, invS);
    newton_apply_iter(y, x, Arow0, nfS, dginv);
    newton_apply_iter(y, x, Arow0, nfS, dginv);
  }

  // iters 15-16: store-build + apply (span 1)
  newton_full_iter<true, true>(y, x, Arow0, eqf, neqf, l, nfS, dginv, invS);
  newton_apply_iter(y, x, Arow0, nfS, dginv);

  // iters 17-20: store-build + applies (spans 1,2,3) -- R14's proven tail
  newton_full_iter<true, true>(y, x, Arow0, eqf, neqf, l, nfS, dginv, invS);
  newton_apply_iter(y, x, Arow0, nfS, dginv);
  newton_apply_iter(y, x, Arow0, nfS, dginv);
  newton_apply_iter(y, x, Arow0, nfS, dginv);

  float4 o;
  o.x = y[0]; o.y = y[1]; o.z = y[2]; o.w = y[3];
  *reinterpret_cast<float4*>(out + g * NV + 4 * l) = o;
}

extern "C" void kernel_launch(void* const* d_in, const int* in_sizes, int n_in,
                              void* d_out, int out_size, void* d_ws, size_t ws_size,
                              hipStream_t stream) {
  const float* y = (const float*)d_in[0];
  const float* x = (const float*)d_in[1];
  const float* A = (const float*)d_in[2];
  float* out = (float*)d_out;
  const int B = in_sizes[0] / NV;  // 32768
  const int threads = B * 4;       // one quad per system
  dim3 block(64);                  // 1 wave/block
  dim3 grid((threads + block.x - 1) / block.x);
  hipLaunchKernelGGL(newton16, grid, block, 0, stream, y, x, A, out, B);
}